// Round 22
// baseline (206.073 us; speedup 1.0000x reference)
//
#include <hip/hip_runtime.h>
#include <hip/hip_bf16.h>
#include <stdint.h>

#define NIN    100000
#define NOUT   200000
#define KOFF   27
#define C      64
#define NPAIR  (KOFF * NIN)            // 2,700,000
#define EPS    1e-5f
#define NCRS   391                     // coarse buckets of 512 output rows
#define CAPC   7680                    // per-coarse capacity (mean 6912, +9 sigma)
#define NBIN   128                     // 4 fine buckets * 32 k-slots
#define IPB_F  2048                    // items per bin_coarse block
#define FIXI   (1.0f / 262144.0f)      // operands pre-scaled by 2^9 each -> 2^18

typedef __attribute__((ext_vector_type(8))) short bf16x8;
typedef __attribute__((ext_vector_type(4))) float f32x4;

// ---------------- fp32 -> bf16 conversion, pre-scaled by 2^9 ---------------
__global__ __launch_bounds__(256)
void cvt_bf16_kernel(const float* __restrict__ src, ushort* __restrict__ dst, int n8)
{
    int t = blockIdx.x * 256 + threadIdx.x;
    if (t >= n8) return;
    const float4* s4 = reinterpret_cast<const float4*>(src) + (size_t)t * 2;
    float4 a = s4[0], b = s4[1];
    float v[8] = {a.x, a.y, a.z, a.w, b.x, b.y, b.z, b.w};
    union { ushort u[8]; uint4 q; } pk;
    #pragma unroll
    for (int j = 0; j < 8; ++j) {
        __hip_bfloat16 h = __float2bfloat16(v[j] * 512.0f);
        pk.u[j] = *reinterpret_cast<ushort*>(&h);
    }
    reinterpret_cast<uint4*>(dst)[t] = pk.q;
}

// Weight -> per-lane MFMA fragment order, bf16, pre-scaled by 2^9.
// wfrag[((k*4+nt)*2+kc)*64 + lane][j] = W[k][kc*32+8*(lane>>4)+j][nt*16+(lane&15)]
__global__ __launch_bounds__(256)
void cvt_wfrag_kernel(const float* __restrict__ w, ushort* __restrict__ wfrag)
{
    int t = blockIdx.x * 256 + threadIdx.x;
    if (t >= KOFF * 4 * 2 * 64) return;
    const int lane = t & 63;
    const int f    = t >> 6;
    const int kc   = f & 1;
    const int nt   = (f >> 1) & 3;
    const int k    = f >> 3;
    const int m16  = lane & 15;
    const int q    = lane >> 4;
    union { ushort u[8]; uint4 v; } pk;
    #pragma unroll
    for (int j = 0; j < 8; ++j) {
        const int ci = kc * 32 + 8 * q + j;
        const int co = nt * 16 + m16;
        __hip_bfloat16 h = __float2bfloat16(w[(size_t)k * 4096 + ci * 64 + co] * 512.0f);
        pk.u[j] = *reinterpret_cast<ushort*>(&h);
    }
    reinterpret_cast<uint4*>(wfrag)[t] = pk.v;
}

// ---------------- Phase B1: coarse binning with sorted writes --------------
// Bucket = oi >> 9 (512 rows). Payload: bits[0,17)=ii  [17,22)=k  [22,31)=oi&511.
__global__ __launch_bounds__(256)
void bin_coarse_kernel(const int* __restrict__ in_idx, const int* __restrict__ out_idx,
                       int* __restrict__ gcur, uint32_t* __restrict__ binned)
{
    __shared__ uint32_t staged[IPB_F];
    __shared__ ushort   sbkt[IPB_F];
    __shared__ int hist[NCRS];
    __shared__ int lbase[NCRS];
    __shared__ int gd[NCRS];
    __shared__ int cur[NCRS];
    __shared__ int s[256];

    const int t  = threadIdx.x;
    const int t0 = blockIdx.x * IPB_F;
    int n = NPAIR - t0;
    if (n < 0) n = 0;
    if (n > IPB_F) n = IPB_F;

    for (int i = t; i < NCRS; i += 256) hist[i] = 0;
    __syncthreads();

    #pragma unroll 4
    for (int j = 0; j < IPB_F / 256; ++j) {
        int i = j * 256 + t;
        if (i < n) atomicAdd(&hist[out_idx[t0 + i] >> 9], 1);
    }
    __syncthreads();

    // exclusive scan over NCRS buckets (2 per thread)
    {
        const int i0 = 2 * t, i1 = 2 * t + 1;
        int v0 = (i0 < NCRS) ? hist[i0] : 0;
        int v1 = (i1 < NCRS) ? hist[i1] : 0;
        s[t] = v0 + v1;
        __syncthreads();
        for (int off = 1; off < 256; off <<= 1) {
            int x = (t >= off) ? s[t - off] : 0;
            __syncthreads();
            s[t] += x;
            __syncthreads();
        }
        int tb = s[t] - (v0 + v1);
        if (i0 < NCRS) lbase[i0] = tb;
        if (i1 < NCRS) lbase[i1] = tb + v0;
    }
    __syncthreads();

    for (int i = t; i < NCRS; i += 256) {
        int cnt = hist[i];
        int gb  = cnt ? atomicAdd(&gcur[i], cnt) : 0;
        gd[i]   = gb - lbase[i];
        cur[i]  = lbase[i];
    }
    __syncthreads();

    #pragma unroll 4
    for (int j = 0; j < IPB_F / 256; ++j) {
        int i = j * 256 + t;
        if (i < n) {
            int tt  = t0 + i;
            int oi  = out_idx[tt];
            int k   = tt / NIN;
            int bkt = oi >> 9;
            int pos = atomicAdd(&cur[bkt], 1);
            staged[pos] = ((uint32_t)(oi & 511) << 22)
                        | ((uint32_t)k << 17)
                        | (uint32_t)in_idx[tt];
            sbkt[pos] = (ushort)bkt;
        }
    }
    __syncthreads();

    for (int i = t; i < n; i += 256) {
        int b  = sbkt[i];
        int gp = gd[b] + i;
        if ((unsigned)gp < (unsigned)CAPC)
            binned[(size_t)b * CAPC + gp] = staged[i];
    }
}

// ---------------- Phase B2: fine sort by (fine bucket, k), in place --------
// bin = (row9>>7)*32 + k -> 128 bins; 129-entry offset table per cb.
__global__ __launch_bounds__(256)
void bin_fine_kernel(const int* __restrict__ gcur, uint32_t* __restrict__ binned,
                     int* __restrict__ foff)
{
    __shared__ uint32_t staged[CAPC];
    __shared__ int hist[NBIN], base[NBIN + 1], cur[NBIN];

    const int cb = blockIdx.x;
    const int t  = threadIdx.x;
    uint32_t* seg = binned + (size_t)cb * CAPC;
    int n = gcur[cb];
    if (n > CAPC) n = CAPC;

    if (t < NBIN) hist[t] = 0;
    __syncthreads();
    for (int i = t; i < n; i += 256) {
        uint32_t pl = seg[i];
        int b = (int)(((pl >> 29) & 3) * 32 + ((pl >> 17) & 31));
        atomicAdd(&hist[b], 1);
    }
    __syncthreads();
    if (t < NBIN) base[t + 1] = hist[t];
    __syncthreads();
    for (int off = 1; off < NBIN; off <<= 1) {
        int x = 0;
        if (t < NBIN && t >= off) x = base[t + 1 - off];
        __syncthreads();
        if (t < NBIN) base[t + 1] += x;
        __syncthreads();
    }
    if (t == 0) base[0] = 0;
    __syncthreads();
    if (t < NBIN) cur[t] = base[t + 1] - hist[t];
    __syncthreads();
    for (int i = t; i < n; i += 256) {
        uint32_t pl = seg[i];
        int b = (int)(((pl >> 29) & 3) * 32 + ((pl >> 17) & 31));
        int pos = atomicAdd(&cur[b], 1);
        staged[pos] = pl;
    }
    __syncthreads();
    for (int i = t; i < n; i += 256) seg[i] = staged[i];
    if (t <= NBIN) foff[(size_t)cb * (NBIN + 1) + t] = base[t];
}

// ---------------- Phase C: fused gather-MFMA + int-LDS scatter + BN/ReLU ---
// Round-21 structure with the accumulator shrunk to EXACTLY 32 KB: pad
// (ACCW=65) replaced by XOR swizzle col' = (c&~3) ^ ((lr&15)<<2), testing
// the hypothesis that the 33.3 KB request halved block residency. 512-thread
// blocks, wave w owns whole k-runs (k = w, w+8, ...), 2-tile ILP, operands
// pre-scaled 2^9 each, native int ds_add (fp LDS atomics = CAS livelock).
__global__ __launch_bounds__(512)
void fused_conv_kernel(const ushort* __restrict__ featsb,   // [NIN][C] bf16 x512
                       const ushort* __restrict__ wfragb,   // fragment-order x512
                       const uint32_t* __restrict__ binned,
                       const int* __restrict__ foff,
                       const float* __restrict__ gamma,
                       const float* __restrict__ beta,
                       const float* __restrict__ mean,
                       const float* __restrict__ var,
                       float* __restrict__ out)
{
    __shared__ int acc[128 * 64];          // exactly 32 KB fixed-point acc

    const int cb   = blockIdx.x;
    const int fb   = blockIdx.y;           // 0..3
    const int t    = threadIdx.x;          // 0..511
    const int wave = t >> 6;               // 0..7
    const int lane = t & 63;
    const int m16  = lane & 15;
    const int q    = lane >> 4;

    for (int i = t; i < 128 * 64; i += 512) acc[i] = 0;
    __syncthreads();

    const uint32_t* seg = binned + (size_t)cb * CAPC;
    const int* fo = foff + (size_t)cb * (NBIN + 1) + fb * 32;
    const bf16x8* wf = reinterpret_cast<const bf16x8*>(wfragb);

    for (int k = wave; k < KOFF; k += 8) {
        const int js = fo[k], je = fo[k + 1];
        if (js >= je) continue;

        bf16x8 xf[4][2];
        #pragma unroll
        for (int nt = 0; nt < 4; ++nt)
            #pragma unroll
            for (int kc = 0; kc < 2; ++kc)
                xf[nt][kc] = wf[(size_t)((k * 4 + nt) * 2 + kc) * 64 + lane];

        for (int base = js; base < je; base += 32) {
            // ---- issue both tiles' load chains up front ----
            const int idxA    = base + m16;
            const bool validA = idxA < je;
            const uint32_t plA = seg[validA ? idxA : je - 1];
            const int iiA = plA & 0x1FFFF;
            const int lrA = (int)((plA >> 22) & 127);
            const ushort* frA = featsb + (size_t)iiA * C;
            bf16x8 yA0 = *reinterpret_cast<const bf16x8*>(frA + 8 * q);
            bf16x8 yA1 = *reinterpret_cast<const bf16x8*>(frA + 32 + 8 * q);
            if (!validA) { yA0 = bf16x8{0,0,0,0,0,0,0,0}; yA1 = bf16x8{0,0,0,0,0,0,0,0}; }

            const bool doB = (base + 16) < je;       // wave-uniform
            bf16x8 yB0 = {0,0,0,0,0,0,0,0}, yB1 = {0,0,0,0,0,0,0,0};
            int lrB = 0;
            if (doB) {
                const int idxB    = base + 16 + m16;
                const bool validB = idxB < je;
                const uint32_t plB = seg[validB ? idxB : je - 1];
                const int iiB = plB & 0x1FFFF;
                lrB = (int)((plB >> 22) & 127);
                const ushort* frB = featsb + (size_t)iiB * C;
                yB0 = *reinterpret_cast<const bf16x8*>(frB + 8 * q);
                yB1 = *reinterpret_cast<const bf16x8*>(frB + 32 + 8 * q);
                if (!validB) { yB0 = bf16x8{0,0,0,0,0,0,0,0}; yB1 = bf16x8{0,0,0,0,0,0,0,0}; }
            }

            // ---- tile A compute + swizzled scatter ----
            {
                f32x4 c0 = {0,0,0,0}, c1 = {0,0,0,0}, c2 = {0,0,0,0}, c3 = {0,0,0,0};
                c0 = __builtin_amdgcn_mfma_f32_16x16x32_bf16(xf[0][0], yA0, c0, 0, 0, 0);
                c1 = __builtin_amdgcn_mfma_f32_16x16x32_bf16(xf[1][0], yA0, c1, 0, 0, 0);
                c2 = __builtin_amdgcn_mfma_f32_16x16x32_bf16(xf[2][0], yA0, c2, 0, 0, 0);
                c3 = __builtin_amdgcn_mfma_f32_16x16x32_bf16(xf[3][0], yA0, c3, 0, 0, 0);
                c0 = __builtin_amdgcn_mfma_f32_16x16x32_bf16(xf[0][1], yA1, c0, 0, 0, 0);
                c1 = __builtin_amdgcn_mfma_f32_16x16x32_bf16(xf[1][1], yA1, c1, 0, 0, 0);
                c2 = __builtin_amdgcn_mfma_f32_16x16x32_bf16(xf[2][1], yA1, c2, 0, 0, 0);
                c3 = __builtin_amdgcn_mfma_f32_16x16x32_bf16(xf[3][1], yA1, c3, 0, 0, 0);

                const int swz = (lrA & 15) << 2;
                int* arow = acc + lrA * 64;
                #pragma unroll
                for (int r = 0; r < 4; ++r)
                    atomicAdd(&arow[((q * 4 +  0) ^ swz) + r], __float2int_rn(c0[r]));
                #pragma unroll
                for (int r = 0; r < 4; ++r)
                    atomicAdd(&arow[((q * 4 + 16) ^ swz) + r], __float2int_rn(c1[r]));
                #pragma unroll
                for (int r = 0; r < 4; ++r)
                    atomicAdd(&arow[((q * 4 + 32) ^ swz) + r], __float2int_rn(c2[r]));
                #pragma unroll
                for (int r = 0; r < 4; ++r)
                    atomicAdd(&arow[((q * 4 + 48) ^ swz) + r], __float2int_rn(c3[r]));
            }

            // ---- tile B compute + swizzled scatter ----
            if (doB) {
                f32x4 c0 = {0,0,0,0}, c1 = {0,0,0,0}, c2 = {0,0,0,0}, c3 = {0,0,0,0};
                c0 = __builtin_amdgcn_mfma_f32_16x16x32_bf16(xf[0][0], yB0, c0, 0, 0, 0);
                c1 = __builtin_amdgcn_mfma_f32_16x16x32_bf16(xf[1][0], yB0, c1, 0, 0, 0);
                c2 = __builtin_amdgcn_mfma_f32_16x16x32_bf16(xf[2][0], yB0, c2, 0, 0, 0);
                c3 = __builtin_amdgcn_mfma_f32_16x16x32_bf16(xf[3][0], yB0, c3, 0, 0, 0);
                c0 = __builtin_amdgcn_mfma_f32_16x16x32_bf16(xf[0][1], yB1, c0, 0, 0, 0);
                c1 = __builtin_amdgcn_mfma_f32_16x16x32_bf16(xf[1][1], yB1, c1, 0, 0, 0);
                c2 = __builtin_amdgcn_mfma_f32_16x16x32_bf16(xf[2][1], yB1, c2, 0, 0, 0);
                c3 = __builtin_amdgcn_mfma_f32_16x16x32_bf16(xf[3][1], yB1, c3, 0, 0, 0);

                const int swz = (lrB & 15) << 2;
                int* arow = acc + lrB * 64;
                #pragma unroll
                for (int r = 0; r < 4; ++r)
                    atomicAdd(&arow[((q * 4 +  0) ^ swz) + r], __float2int_rn(c0[r]));
                #pragma unroll
                for (int r = 0; r < 4; ++r)
                    atomicAdd(&arow[((q * 4 + 16) ^ swz) + r], __float2int_rn(c1[r]));
                #pragma unroll
                for (int r = 0; r < 4; ++r)
                    atomicAdd(&arow[((q * 4 + 32) ^ swz) + r], __float2int_rn(c2[r]));
                #pragma unroll
                for (int r = 0; r < 4; ++r)
                    atomicAdd(&arow[((q * 4 + 48) ^ swz) + r], __float2int_rn(c3[r]));
            }
        }
    }
    __syncthreads();

    // ---- BN + ReLU epilogue, single write of out (swizzle-aware reads) ----
    const int cp = t & 15;
    float sc[4], sh[4];
    #pragma unroll
    for (int r = 0; r < 4; ++r) {
        const int c = cp * 4 + r;
        float s = gamma[c] * rsqrtf(var[c] + EPS);
        sc[r] = s;
        sh[r] = beta[c] - mean[c] * s;
    }
    float4* out4 = reinterpret_cast<float4*>(out);
    #pragma unroll
    for (int rep = 0; rep < 4; ++rep) {
        const int i   = t + rep * 512;
        const int rl  = i >> 4;
        const int row = cb * 512 + fb * 128 + rl;
        if (row < NOUT) {
            const int swz = (rl & 15) << 2;
            const int* ap = acc + rl * 64 + ((cp * 4) ^ swz);
            float v0 = fmaf((float)ap[0] * FIXI, sc[0], sh[0]); v0 = v0 > 0.f ? v0 : 0.f;
            float v1 = fmaf((float)ap[1] * FIXI, sc[1], sh[1]); v1 = v1 > 0.f ? v1 : 0.f;
            float v2 = fmaf((float)ap[2] * FIXI, sc[2], sh[2]); v2 = v2 > 0.f ? v2 : 0.f;
            float v3 = fmaf((float)ap[3] * FIXI, sc[3], sh[3]); v3 = v3 > 0.f ? v3 : 0.f;
            out4[(size_t)row * 16 + cp] = make_float4(v0, v1, v2, v3);
        }
    }
}

// ---------------- Fallback (atomic path, tiny ws) --------------------------
__global__ __launch_bounds__(256)
void conv_scatter_kernel(const float* __restrict__ feats,
                         const float* __restrict__ weight,
                         const int*   __restrict__ in_idx,
                         const int*   __restrict__ out_idx,
                         float*       __restrict__ out)
{
    const int k    = blockIdx.y;
    const int lane = threadIdx.x & 63;
    const int wave = threadIdx.x >> 6;
    const int wavesInGrid = gridDim.x * 4;
    const int waveId      = blockIdx.x * 4 + wave;

    const float* wk = weight + (size_t)k * C * C + lane;
    float w[C];
    #pragma unroll
    for (int ci = 0; ci < C; ++ci) w[ci] = wk[(size_t)ci * C];

    const int* ii_k = in_idx  + (size_t)k * NIN;
    const int* oi_k = out_idx + (size_t)k * NIN;

    for (int r = waveId; r < NIN; r += wavesInGrid) {
        const int ii = ii_k[r];
        const int oi = oi_k[r];
        const float4* frow = reinterpret_cast<const float4*>(feats + (size_t)ii * C);
        float acc = 0.0f;
        #pragma unroll
        for (int j = 0; j < C / 4; ++j) {
            float4 f = frow[j];
            acc = fmaf(f.x, w[4 * j + 0], acc);
            acc = fmaf(f.y, w[4 * j + 1], acc);
            acc = fmaf(f.z, w[4 * j + 2], acc);
            acc = fmaf(f.w, w[4 * j + 3], acc);
        }
        atomicAdd(out + (size_t)oi * C + lane, acc);
    }
}

__global__ __launch_bounds__(256)
void bn_relu_kernel(float* __restrict__ out,
                    const float* __restrict__ gamma,
                    const float* __restrict__ beta,
                    const float* __restrict__ mean,
                    const float* __restrict__ var)
{
    const int total4 = NOUT * C / 4;
    int idx = blockIdx.x * blockDim.x + threadIdx.x;
    if (idx >= total4) return;
    const int c0 = (idx * 4) & (C - 1);
    float sc[4], sh[4];
    #pragma unroll
    for (int j = 0; j < 4; ++j) {
        const int c  = c0 + j;
        const float s = gamma[c] * rsqrtf(var[c] + EPS);
        sc[j] = s;
        sh[j] = beta[c] - mean[c] * s;
    }
    float4* p = reinterpret_cast<float4*>(out) + idx;
    float4 v = *p;
    v.x = fmaf(v.x, sc[0], sh[0]); v.x = v.x > 0.f ? v.x : 0.f;
    v.y = fmaf(v.y, sc[1], sh[1]); v.y = v.y > 0.f ? v.y : 0.f;
    v.z = fmaf(v.z, sc[2], sh[2]); v.z = v.z > 0.f ? v.z : 0.f;
    v.w = fmaf(v.w, sc[3], sh[3]); v.w = v.w > 0.f ? v.w : 0.f;
    *p = v;
}

// ---------------------------------------------------------------------------
extern "C" void kernel_launch(void* const* d_in, const int* in_sizes, int n_in,
                              void* d_out, int out_size, void* d_ws, size_t ws_size,
                              hipStream_t stream) {
    const float* feats   = (const float*)d_in[0];
    const float* weight  = (const float*)d_in[1];
    const int*   in_idx  = (const int*)  d_in[2];
    const int*   out_idx = (const int*)  d_in[3];
    const float* gamma   = (const float*)d_in[4];
    const float* beta    = (const float*)d_in[5];
    const float* rmean   = (const float*)d_in[6];
    const float* rvar    = (const float*)d_in[7];
    float* out = (float*)d_out;

    auto align = [](size_t x) { return (x + 255) & ~(size_t)255; };

    size_t a = 0;
    size_t oBin = a; a += align((size_t)NCRS * CAPC * 4);          // binned (~12 MB)
    size_t oGc  = a; a += align((size_t)NCRS * 4);                 // gcur
    size_t oFo  = a; a += align((size_t)NCRS * (NBIN + 1) * 4);    // fine offsets
    size_t oFb  = a; a += align((size_t)NIN * C * 2);              // feats bf16 (12.8 MB)
    size_t oWf  = a; a += align((size_t)KOFF * 4 * 2 * 64 * 16);   // W fragments (221 KB)

    if (ws_size < a) {
        hipMemsetAsync(out, 0, (size_t)out_size * sizeof(float), stream);
        dim3 grid(512, KOFF);
        conv_scatter_kernel<<<grid, 256, 0, stream>>>(feats, weight, in_idx, out_idx, out);
        const int total4 = NOUT * C / 4;
        bn_relu_kernel<<<(total4 + 255) / 256, 256, 0, stream>>>(out, gamma, beta, rmean, rvar);
        return;
    }

    char* ws = (char*)d_ws;
    uint32_t* binned = (uint32_t*)(ws + oBin);
    int* gcur        = (int*)(ws + oGc);
    int* foff        = (int*)(ws + oFo);
    ushort* featsb   = (ushort*)(ws + oFb);
    ushort* wfragb   = (ushort*)(ws + oWf);

    // --- conversions (pre-scaled by 2^9 each) ---
    {
        int n8f = NIN * C / 8;
        cvt_bf16_kernel<<<(n8f + 255) / 256, 256, 0, stream>>>(feats, featsb, n8f);
        int nwf = KOFF * 4 * 2 * 64;
        cvt_wfrag_kernel<<<(nwf + 255) / 256, 256, 0, stream>>>(weight, wfragb);
    }

    // --- two-level binning (sorted by coarse bucket, then (fine, k)) ---
    hipMemsetAsync(gcur, 0, (size_t)NCRS * sizeof(int), stream);
    {
        int nbC = (NPAIR + IPB_F - 1) / IPB_F;
        bin_coarse_kernel<<<nbC, 256, 0, stream>>>(in_idx, out_idx, gcur, binned);
        bin_fine_kernel<<<NCRS, 256, 0, stream>>>(gcur, binned, foff);
    }

    // --- fused gather-MFMA-scatter + BN + ReLU, 512-thread blocks ---
    {
        dim3 grid(NCRS, 4);
        fused_conv_kernel<<<grid, 512, 0, stream>>>(featsb, wfragb, binned, foff,
                                                    gamma, beta, rmean, rvar, out);
    }
}

// Round 23
// 180.683 us; speedup vs baseline: 1.1405x; 1.1405x over previous
//
#include <hip/hip_runtime.h>
#include <hip/hip_bf16.h>
#include <stdint.h>

#define NIN    100000
#define NOUT   200000
#define KOFF   27
#define C      64
#define NPAIR  (KOFF * NIN)            // 2,700,000
#define EPS    1e-5f
#define NCRS   391                     // coarse buckets of 512 output rows
#define CAPC   7680                    // per-coarse capacity (mean 6912, +9 sigma)
#define NBIN   128                     // 4 fine buckets * 32 k-slots
#define IPB_F  2048                    // items per bin_coarse block
#define ACCW   65                      // padded acc row stride (65 = 1 mod 32: rows spread banks)
#define FIXI   (1.0f / 262144.0f)      // operands pre-scaled by 2^9 each -> 2^18

typedef __attribute__((ext_vector_type(8))) short bf16x8;
typedef __attribute__((ext_vector_type(4))) float f32x4;

// ---------------- fp32 -> bf16 conversion, pre-scaled by 2^9 ---------------
__global__ __launch_bounds__(256)
void cvt_bf16_kernel(const float* __restrict__ src, ushort* __restrict__ dst, int n8)
{
    int t = blockIdx.x * 256 + threadIdx.x;
    if (t >= n8) return;
    const float4* s4 = reinterpret_cast<const float4*>(src) + (size_t)t * 2;
    float4 a = s4[0], b = s4[1];
    float v[8] = {a.x, a.y, a.z, a.w, b.x, b.y, b.z, b.w};
    union { ushort u[8]; uint4 q; } pk;
    #pragma unroll
    for (int j = 0; j < 8; ++j) {
        __hip_bfloat16 h = __float2bfloat16(v[j] * 512.0f);
        pk.u[j] = *reinterpret_cast<ushort*>(&h);
    }
    reinterpret_cast<uint4*>(dst)[t] = pk.q;
}

// Weight -> per-lane MFMA fragment order, bf16, pre-scaled by 2^9.
// wfrag[((k*4+nt)*2+kc)*64 + lane][j] = W[k][kc*32+8*(lane>>4)+j][nt*16+(lane&15)]
__global__ __launch_bounds__(256)
void cvt_wfrag_kernel(const float* __restrict__ w, ushort* __restrict__ wfrag)
{
    int t = blockIdx.x * 256 + threadIdx.x;
    if (t >= KOFF * 4 * 2 * 64) return;
    const int lane = t & 63;
    const int f    = t >> 6;
    const int kc   = f & 1;
    const int nt   = (f >> 1) & 3;
    const int k    = f >> 3;
    const int m16  = lane & 15;
    const int q    = lane >> 4;
    union { ushort u[8]; uint4 v; } pk;
    #pragma unroll
    for (int j = 0; j < 8; ++j) {
        const int ci = kc * 32 + 8 * q + j;
        const int co = nt * 16 + m16;
        __hip_bfloat16 h = __float2bfloat16(w[(size_t)k * 4096 + ci * 64 + co] * 512.0f);
        pk.u[j] = *reinterpret_cast<ushort*>(&h);
    }
    reinterpret_cast<uint4*>(wfrag)[t] = pk.v;
}

// ---------------- Phase B1: coarse binning with sorted writes --------------
// Bucket = oi >> 9 (512 rows). Payload: bits[0,17)=ii  [17,22)=k  [22,31)=oi&511.
__global__ __launch_bounds__(256)
void bin_coarse_kernel(const int* __restrict__ in_idx, const int* __restrict__ out_idx,
                       int* __restrict__ gcur, uint32_t* __restrict__ binned)
{
    __shared__ uint32_t staged[IPB_F];
    __shared__ ushort   sbkt[IPB_F];
    __shared__ int hist[NCRS];
    __shared__ int lbase[NCRS];
    __shared__ int gd[NCRS];
    __shared__ int cur[NCRS];
    __shared__ int s[256];

    const int t  = threadIdx.x;
    const int t0 = blockIdx.x * IPB_F;
    int n = NPAIR - t0;
    if (n < 0) n = 0;
    if (n > IPB_F) n = IPB_F;

    for (int i = t; i < NCRS; i += 256) hist[i] = 0;
    __syncthreads();

    #pragma unroll 4
    for (int j = 0; j < IPB_F / 256; ++j) {
        int i = j * 256 + t;
        if (i < n) atomicAdd(&hist[out_idx[t0 + i] >> 9], 1);
    }
    __syncthreads();

    // exclusive scan over NCRS buckets (2 per thread)
    {
        const int i0 = 2 * t, i1 = 2 * t + 1;
        int v0 = (i0 < NCRS) ? hist[i0] : 0;
        int v1 = (i1 < NCRS) ? hist[i1] : 0;
        s[t] = v0 + v1;
        __syncthreads();
        for (int off = 1; off < 256; off <<= 1) {
            int x = (t >= off) ? s[t - off] : 0;
            __syncthreads();
            s[t] += x;
            __syncthreads();
        }
        int tb = s[t] - (v0 + v1);
        if (i0 < NCRS) lbase[i0] = tb;
        if (i1 < NCRS) lbase[i1] = tb + v0;
    }
    __syncthreads();

    for (int i = t; i < NCRS; i += 256) {
        int cnt = hist[i];
        int gb  = cnt ? atomicAdd(&gcur[i], cnt) : 0;
        gd[i]   = gb - lbase[i];
        cur[i]  = lbase[i];
    }
    __syncthreads();

    #pragma unroll 4
    for (int j = 0; j < IPB_F / 256; ++j) {
        int i = j * 256 + t;
        if (i < n) {
            int tt  = t0 + i;
            int oi  = out_idx[tt];
            int k   = tt / NIN;
            int bkt = oi >> 9;
            int pos = atomicAdd(&cur[bkt], 1);
            staged[pos] = ((uint32_t)(oi & 511) << 22)
                        | ((uint32_t)k << 17)
                        | (uint32_t)in_idx[tt];
            sbkt[pos] = (ushort)bkt;
        }
    }
    __syncthreads();

    for (int i = t; i < n; i += 256) {
        int b  = sbkt[i];
        int gp = gd[b] + i;
        if ((unsigned)gp < (unsigned)CAPC)
            binned[(size_t)b * CAPC + gp] = staged[i];
    }
}

// ---------------- Phase B2: fine sort by (fine bucket, k), in place --------
// bin = (row9>>7)*32 + k -> 128 bins; 129-entry offset table per cb.
__global__ __launch_bounds__(256)
void bin_fine_kernel(const int* __restrict__ gcur, uint32_t* __restrict__ binned,
                     int* __restrict__ foff)
{
    __shared__ uint32_t staged[CAPC];
    __shared__ int hist[NBIN], base[NBIN + 1], cur[NBIN];

    const int cb = blockIdx.x;
    const int t  = threadIdx.x;
    uint32_t* seg = binned + (size_t)cb * CAPC;
    int n = gcur[cb];
    if (n > CAPC) n = CAPC;

    if (t < NBIN) hist[t] = 0;
    __syncthreads();
    for (int i = t; i < n; i += 256) {
        uint32_t pl = seg[i];
        int b = (int)(((pl >> 29) & 3) * 32 + ((pl >> 17) & 31));
        atomicAdd(&hist[b], 1);
    }
    __syncthreads();
    if (t < NBIN) base[t + 1] = hist[t];
    __syncthreads();
    for (int off = 1; off < NBIN; off <<= 1) {
        int x = 0;
        if (t < NBIN && t >= off) x = base[t + 1 - off];
        __syncthreads();
        if (t < NBIN) base[t + 1] += x;
        __syncthreads();
    }
    if (t == 0) base[0] = 0;
    __syncthreads();
    if (t < NBIN) cur[t] = base[t + 1] - hist[t];
    __syncthreads();
    for (int i = t; i < n; i += 256) {
        uint32_t pl = seg[i];
        int b = (int)(((pl >> 29) & 3) * 32 + ((pl >> 17) & 31));
        int pos = atomicAdd(&cur[b], 1);
        staged[pos] = pl;
    }
    __syncthreads();
    for (int i = t; i < n; i += 256) seg[i] = staged[i];
    if (t <= NBIN) foff[(size_t)cb * (NBIN + 1) + t] = base[t];
}

// ---------------- Phase C: fused gather-MFMA + int-LDS scatter + BN/ReLU ---
// Round-21 champion: 512-thread blocks (32-wave/CU cap), wave w owns whole
// k-runs (k = w, w+8, ...), 2-tile ILP, padded acc (ACCW=65; 65=1 mod 32
// spreads rows across banks), operands pre-scaled 2^9 each, native int
// ds_add (fp LDS atomics = CAS livelock, rounds 7/14).
__global__ __launch_bounds__(512)
void fused_conv_kernel(const ushort* __restrict__ featsb,   // [NIN][C] bf16 x512
                       const ushort* __restrict__ wfragb,   // fragment-order x512
                       const uint32_t* __restrict__ binned,
                       const int* __restrict__ foff,
                       const float* __restrict__ gamma,
                       const float* __restrict__ beta,
                       const float* __restrict__ mean,
                       const float* __restrict__ var,
                       float* __restrict__ out)
{
    __shared__ int acc[128 * ACCW];        // 33.3 KB fixed-point accumulator

    const int cb   = blockIdx.x;
    const int fb   = blockIdx.y;           // 0..3
    const int t    = threadIdx.x;          // 0..511
    const int wave = t >> 6;               // 0..7
    const int lane = t & 63;
    const int m16  = lane & 15;
    const int q    = lane >> 4;

    for (int i = t; i < 128 * ACCW; i += 512) acc[i] = 0;
    __syncthreads();

    const uint32_t* seg = binned + (size_t)cb * CAPC;
    const int* fo = foff + (size_t)cb * (NBIN + 1) + fb * 32;
    const bf16x8* wf = reinterpret_cast<const bf16x8*>(wfragb);

    for (int k = wave; k < KOFF; k += 8) {
        const int js = fo[k], je = fo[k + 1];
        if (js >= je) continue;

        bf16x8 xf[4][2];
        #pragma unroll
        for (int nt = 0; nt < 4; ++nt)
            #pragma unroll
            for (int kc = 0; kc < 2; ++kc)
                xf[nt][kc] = wf[(size_t)((k * 4 + nt) * 2 + kc) * 64 + lane];

        for (int base = js; base < je; base += 32) {
            // ---- issue both tiles' load chains up front ----
            const int idxA    = base + m16;
            const bool validA = idxA < je;
            const uint32_t plA = seg[validA ? idxA : je - 1];
            const int iiA = plA & 0x1FFFF;
            const int lrA = (int)((plA >> 22) & 127);
            const ushort* frA = featsb + (size_t)iiA * C;
            bf16x8 yA0 = *reinterpret_cast<const bf16x8*>(frA + 8 * q);
            bf16x8 yA1 = *reinterpret_cast<const bf16x8*>(frA + 32 + 8 * q);
            if (!validA) { yA0 = bf16x8{0,0,0,0,0,0,0,0}; yA1 = bf16x8{0,0,0,0,0,0,0,0}; }

            const bool doB = (base + 16) < je;       // wave-uniform
            bf16x8 yB0 = {0,0,0,0,0,0,0,0}, yB1 = {0,0,0,0,0,0,0,0};
            int lrB = 0;
            if (doB) {
                const int idxB    = base + 16 + m16;
                const bool validB = idxB < je;
                const uint32_t plB = seg[validB ? idxB : je - 1];
                const int iiB = plB & 0x1FFFF;
                lrB = (int)((plB >> 22) & 127);
                const ushort* frB = featsb + (size_t)iiB * C;
                yB0 = *reinterpret_cast<const bf16x8*>(frB + 8 * q);
                yB1 = *reinterpret_cast<const bf16x8*>(frB + 32 + 8 * q);
                if (!validB) { yB0 = bf16x8{0,0,0,0,0,0,0,0}; yB1 = bf16x8{0,0,0,0,0,0,0,0}; }
            }

            // ---- tile A compute + scatter ----
            {
                f32x4 c0 = {0,0,0,0}, c1 = {0,0,0,0}, c2 = {0,0,0,0}, c3 = {0,0,0,0};
                c0 = __builtin_amdgcn_mfma_f32_16x16x32_bf16(xf[0][0], yA0, c0, 0, 0, 0);
                c1 = __builtin_amdgcn_mfma_f32_16x16x32_bf16(xf[1][0], yA0, c1, 0, 0, 0);
                c2 = __builtin_amdgcn_mfma_f32_16x16x32_bf16(xf[2][0], yA0, c2, 0, 0, 0);
                c3 = __builtin_amdgcn_mfma_f32_16x16x32_bf16(xf[3][0], yA0, c3, 0, 0, 0);
                c0 = __builtin_amdgcn_mfma_f32_16x16x32_bf16(xf[0][1], yA1, c0, 0, 0, 0);
                c1 = __builtin_amdgcn_mfma_f32_16x16x32_bf16(xf[1][1], yA1, c1, 0, 0, 0);
                c2 = __builtin_amdgcn_mfma_f32_16x16x32_bf16(xf[2][1], yA1, c2, 0, 0, 0);
                c3 = __builtin_amdgcn_mfma_f32_16x16x32_bf16(xf[3][1], yA1, c3, 0, 0, 0);

                int* arow = acc + lrA * ACCW + q * 4;
                #pragma unroll
                for (int r = 0; r < 4; ++r)
                    atomicAdd(&arow[ 0 + r], __float2int_rn(c0[r]));
                #pragma unroll
                for (int r = 0; r < 4; ++r)
                    atomicAdd(&arow[16 + r], __float2int_rn(c1[r]));
                #pragma unroll
                for (int r = 0; r < 4; ++r)
                    atomicAdd(&arow[32 + r], __float2int_rn(c2[r]));
                #pragma unroll
                for (int r = 0; r < 4; ++r)
                    atomicAdd(&arow[48 + r], __float2int_rn(c3[r]));
            }

            // ---- tile B compute + scatter ----
            if (doB) {
                f32x4 c0 = {0,0,0,0}, c1 = {0,0,0,0}, c2 = {0,0,0,0}, c3 = {0,0,0,0};
                c0 = __builtin_amdgcn_mfma_f32_16x16x32_bf16(xf[0][0], yB0, c0, 0, 0, 0);
                c1 = __builtin_amdgcn_mfma_f32_16x16x32_bf16(xf[1][0], yB0, c1, 0, 0, 0);
                c2 = __builtin_amdgcn_mfma_f32_16x16x32_bf16(xf[2][0], yB0, c2, 0, 0, 0);
                c3 = __builtin_amdgcn_mfma_f32_16x16x32_bf16(xf[3][0], yB0, c3, 0, 0, 0);
                c0 = __builtin_amdgcn_mfma_f32_16x16x32_bf16(xf[0][1], yB1, c0, 0, 0, 0);
                c1 = __builtin_amdgcn_mfma_f32_16x16x32_bf16(xf[1][1], yB1, c1, 0, 0, 0);
                c2 = __builtin_amdgcn_mfma_f32_16x16x32_bf16(xf[2][1], yB1, c2, 0, 0, 0);
                c3 = __builtin_amdgcn_mfma_f32_16x16x32_bf16(xf[3][1], yB1, c3, 0, 0, 0);

                int* arow = acc + lrB * ACCW + q * 4;
                #pragma unroll
                for (int r = 0; r < 4; ++r)
                    atomicAdd(&arow[ 0 + r], __float2int_rn(c0[r]));
                #pragma unroll
                for (int r = 0; r < 4; ++r)
                    atomicAdd(&arow[16 + r], __float2int_rn(c1[r]));
                #pragma unroll
                for (int r = 0; r < 4; ++r)
                    atomicAdd(&arow[32 + r], __float2int_rn(c2[r]));
                #pragma unroll
                for (int r = 0; r < 4; ++r)
                    atomicAdd(&arow[48 + r], __float2int_rn(c3[r]));
            }
        }
    }
    __syncthreads();

    // ---- BN + ReLU epilogue, single write of out ----
    const int cp = t & 15;
    float sc[4], sh[4];
    #pragma unroll
    for (int r = 0; r < 4; ++r) {
        const int c = cp * 4 + r;
        float s = gamma[c] * rsqrtf(var[c] + EPS);
        sc[r] = s;
        sh[r] = beta[c] - mean[c] * s;
    }
    float4* out4 = reinterpret_cast<float4*>(out);
    #pragma unroll
    for (int rep = 0; rep < 4; ++rep) {
        const int i   = t + rep * 512;
        const int rl  = i >> 4;
        const int row = cb * 512 + fb * 128 + rl;
        if (row < NOUT) {
            const int* ap = &acc[rl * ACCW + cp * 4];
            float v0 = fmaf((float)ap[0] * FIXI, sc[0], sh[0]); v0 = v0 > 0.f ? v0 : 0.f;
            float v1 = fmaf((float)ap[1] * FIXI, sc[1], sh[1]); v1 = v1 > 0.f ? v1 : 0.f;
            float v2 = fmaf((float)ap[2] * FIXI, sc[2], sh[2]); v2 = v2 > 0.f ? v2 : 0.f;
            float v3 = fmaf((float)ap[3] * FIXI, sc[3], sh[3]); v3 = v3 > 0.f ? v3 : 0.f;
            out4[(size_t)row * 16 + cp] = make_float4(v0, v1, v2, v3);
        }
    }
}

// ---------------- Fallback (atomic path, tiny ws) --------------------------
__global__ __launch_bounds__(256)
void conv_scatter_kernel(const float* __restrict__ feats,
                         const float* __restrict__ weight,
                         const int*   __restrict__ in_idx,
                         const int*   __restrict__ out_idx,
                         float*       __restrict__ out)
{
    const int k    = blockIdx.y;
    const int lane = threadIdx.x & 63;
    const int wave = threadIdx.x >> 6;
    const int wavesInGrid = gridDim.x * 4;
    const int waveId      = blockIdx.x * 4 + wave;

    const float* wk = weight + (size_t)k * C * C + lane;
    float w[C];
    #pragma unroll
    for (int ci = 0; ci < C; ++ci) w[ci] = wk[(size_t)ci * C];

    const int* ii_k = in_idx  + (size_t)k * NIN;
    const int* oi_k = out_idx + (size_t)k * NIN;

    for (int r = waveId; r < NIN; r += wavesInGrid) {
        const int ii = ii_k[r];
        const int oi = oi_k[r];
        const float4* frow = reinterpret_cast<const float4*>(feats + (size_t)ii * C);
        float acc = 0.0f;
        #pragma unroll
        for (int j = 0; j < C / 4; ++j) {
            float4 f = frow[j];
            acc = fmaf(f.x, w[4 * j + 0], acc);
            acc = fmaf(f.y, w[4 * j + 1], acc);
            acc = fmaf(f.z, w[4 * j + 2], acc);
            acc = fmaf(f.w, w[4 * j + 3], acc);
        }
        atomicAdd(out + (size_t)oi * C + lane, acc);
    }
}

__global__ __launch_bounds__(256)
void bn_relu_kernel(float* __restrict__ out,
                    const float* __restrict__ gamma,
                    const float* __restrict__ beta,
                    const float* __restrict__ mean,
                    const float* __restrict__ var)
{
    const int total4 = NOUT * C / 4;
    int idx = blockIdx.x * blockDim.x + threadIdx.x;
    if (idx >= total4) return;
    const int c0 = (idx * 4) & (C - 1);
    float sc[4], sh[4];
    #pragma unroll
    for (int j = 0; j < 4; ++j) {
        const int c  = c0 + j;
        const float s = gamma[c] * rsqrtf(var[c] + EPS);
        sc[j] = s;
        sh[j] = beta[c] - mean[c] * s;
    }
    float4* p = reinterpret_cast<float4*>(out) + idx;
    float4 v = *p;
    v.x = fmaf(v.x, sc[0], sh[0]); v.x = v.x > 0.f ? v.x : 0.f;
    v.y = fmaf(v.y, sc[1], sh[1]); v.y = v.y > 0.f ? v.y : 0.f;
    v.z = fmaf(v.z, sc[2], sh[2]); v.z = v.z > 0.f ? v.z : 0.f;
    v.w = fmaf(v.w, sc[3], sh[3]); v.w = v.w > 0.f ? v.w : 0.f;
    *p = v;
}

// ---------------------------------------------------------------------------
extern "C" void kernel_launch(void* const* d_in, const int* in_sizes, int n_in,
                              void* d_out, int out_size, void* d_ws, size_t ws_size,
                              hipStream_t stream) {
    const float* feats   = (const float*)d_in[0];
    const float* weight  = (const float*)d_in[1];
    const int*   in_idx  = (const int*)  d_in[2];
    const int*   out_idx = (const int*)  d_in[3];
    const float* gamma   = (const float*)d_in[4];
    const float* beta    = (const float*)d_in[5];
    const float* rmean   = (const float*)d_in[6];
    const float* rvar    = (const float*)d_in[7];
    float* out = (float*)d_out;

    auto align = [](size_t x) { return (x + 255) & ~(size_t)255; };

    size_t a = 0;
    size_t oBin = a; a += align((size_t)NCRS * CAPC * 4);          // binned (~12 MB)
    size_t oGc  = a; a += align((size_t)NCRS * 4);                 // gcur
    size_t oFo  = a; a += align((size_t)NCRS * (NBIN + 1) * 4);    // fine offsets
    size_t oFb  = a; a += align((size_t)NIN * C * 2);              // feats bf16 (12.8 MB)
    size_t oWf  = a; a += align((size_t)KOFF * 4 * 2 * 64 * 16);   // W fragments (221 KB)

    if (ws_size < a) {
        hipMemsetAsync(out, 0, (size_t)out_size * sizeof(float), stream);
        dim3 grid(512, KOFF);
        conv_scatter_kernel<<<grid, 256, 0, stream>>>(feats, weight, in_idx, out_idx, out);
        const int total4 = NOUT * C / 4;
        bn_relu_kernel<<<(total4 + 255) / 256, 256, 0, stream>>>(out, gamma, beta, rmean, rvar);
        return;
    }

    char* ws = (char*)d_ws;
    uint32_t* binned = (uint32_t*)(ws + oBin);
    int* gcur        = (int*)(ws + oGc);
    int* foff        = (int*)(ws + oFo);
    ushort* featsb   = (ushort*)(ws + oFb);
    ushort* wfragb   = (ushort*)(ws + oWf);

    // --- conversions (pre-scaled by 2^9 each) ---
    {
        int n8f = NIN * C / 8;
        cvt_bf16_kernel<<<(n8f + 255) / 256, 256, 0, stream>>>(feats, featsb, n8f);
        int nwf = KOFF * 4 * 2 * 64;
        cvt_wfrag_kernel<<<(nwf + 255) / 256, 256, 0, stream>>>(weight, wfragb);
    }

    // --- two-level binning (sorted by coarse bucket, then (fine, k)) ---
    hipMemsetAsync(gcur, 0, (size_t)NCRS * sizeof(int), stream);
    {
        int nbC = (NPAIR + IPB_F - 1) / IPB_F;
        bin_coarse_kernel<<<nbC, 256, 0, stream>>>(in_idx, out_idx, gcur, binned);
        bin_fine_kernel<<<NCRS, 256, 0, stream>>>(gcur, binned, foff);
    }

    // --- fused gather-MFMA-scatter + BN + ReLU, 512-thread blocks ---
    {
        dim3 grid(NCRS, 4);
        fused_conv_kernel<<<grid, 512, 0, stream>>>(featsb, wfragb, binned, foff,
                                                    gamma, beta, rmean, rvar, out);
    }
}